// Round 13
// baseline (1165.727 us; speedup 1.0000x reference)
//
#include <hip/hip_runtime.h>

// Match numpy's rounding exactly: no FMA contraction, same op order as reference.
#pragma clang fp contract(off)

#define B_    4
#define NT_   256
#define NZ_   192
#define NX_   192
#define NREC_ 128
#define DT_   0.001f
#define DH_   10.0f

#define N_CELL  (NZ_ * NX_)        // 36864
#define N_FIELD (B_ * N_CELL)      // 147456

#define K_     8                   // timesteps fused per launch
#define ROWS   3                   // rows owned per block
#define NTHR   1024                // threads per block (16 waves = 4/SIMD)
#define VH     (2 * K_ - 1)        // 15 vel halo rows each side (storage)
#define HS0    (2 * (K_ - 1))      // 14 stress write halo at substep 0
#define VROWS  (ROWS + 2 * VH)     // 33
#define SROWSL (ROWS + 2 * HS0)    // 31  stress LDS rows
#define TILES  (NZ_ / ROWS)        // 64
#define NBLK   (B_ * TILES)        // 256  (one per CU)
#define NX4    (NX_ / 4)           // 48 float4 per row
#define NXCD   8
#define LDS_BYTES ((2 * VROWS + 3 * SROWSL) * NX_ * 4)   // 122112

using f4 = __attribute__((ext_vector_type(4))) float;

__device__ __forceinline__ int imax_(int a, int b) { return a > b ? a : b; }
__device__ __forceinline__ int imin_(int a, int b) { return a < b ? a : b; }
__device__ __forceinline__ f4 LD4(const float* p) { return *reinterpret_cast<const f4*>(p); }
__device__ __forceinline__ void ST4(float* p, f4 v) { *reinterpret_cast<f4*>(p) = v; }

// ---------------- material precompute ----------------
__global__ void mat_kernel(const float* __restrict__ vp, const float* __restrict__ vs,
                           const float* __restrict__ rho,
                           float* __restrict__ lam, float* __restrict__ dtmu,
                           float* __restrict__ lam2mu, float* __restrict__ buoy) {
    int i = blockIdx.x * blockDim.x + threadIdx.x;
    if (i >= N_CELL) return;
    float vpi = vp[i], vsi = vs[i], rhoi = rho[i];
    float vs2 = vsi * vsi;
    float mui = rhoi * vs2;
    float lami = rhoi * (vpi * vpi - 2.0f * vs2);
    lam[i] = lami;
    dtmu[i] = DT_ * mui;             // reference: DT * mu * (...) == (DT*mu) * (...)
    lam2mu[i] = lami + 2.0f * mui;
    buoy[i] = DT_ / rhoi;
}

// One fused substep. Substep 0 reads prior-state fields straight from GLOBAL
// (no separate stage-in phase); later substeps read LDS. Per-element math
// identical to reference (contract off).
template<int S>
__device__ __forceinline__ void substep(
    int tid, int z0, int base, int zv0, int zs0, int sz, int sx, int b, int t0,
    float* __restrict__ vxl, float* __restrict__ vzl,
    float* __restrict__ txxl, float* __restrict__ tzzl, float* __restrict__ txzl,
    const float* __restrict__ vxr, const float* __restrict__ vzr,
    const float* __restrict__ txxr, const float* __restrict__ tzzr,
    const float* __restrict__ txzr,
    const float* __restrict__ lam, const float* __restrict__ dtmu,
    const float* __restrict__ l2m, const float* __restrict__ buoy,
    const float* __restrict__ wav,
    bool rec_ok, int rec_idx, float* __restrict__ out,
    float* __restrict__ vxw, float* __restrict__ vzw,
    float* __restrict__ txxw, float* __restrict__ tzzw, float* __restrict__ txzw) {
    const int t = t0 + S;

    // ---- velocity update on rows [z0-hv, z0+ROWS-1+hv] ----
    {
        constexpr int hv   = 2 * (K_ - 1 - S) + 1;
        constexpr int MAXR = ROWS + 2 * hv;
        constexpr int ITER = (MAXR * NX4 + NTHR - 1) / NTHR;
        const int zlo = imax_(0, z0 - hv);
        const int zhi = imin_(NZ_ - 1, z0 + ROWS - 1 + hv);
        const int n4  = (zhi - zlo + 1) * NX4;
#pragma unroll
        for (int it = 0; it < ITER; ++it) {
            int idx = tid + it * NTHR;
            if (idx < n4) {
                int dz  = idx / NX4;
                int x4i = idx - dz * NX4;
                int x0i = x4i * 4;
                int z   = zlo + dz;
                f4 txo, txn, tzo, tzp, tzm, tzzo, tzzp, vxo, vzo;
                if (S == 0) {
                    int gz  = base + z * NX_ + x0i;
                    int gzm = base + imax_(z - 1, 0) * NX_ + x0i;
                    int gzp = base + imin_(z + 1, NZ_ - 1) * NX_ + x0i;
                    txo  = LD4(txxr + gz);
                    txn  = LD4(txxr + gz + (x4i < NX4 - 1 ? 4 : 0));
                    tzo  = LD4(txzr + gz);
                    tzp  = LD4(txzr + gz - (x4i > 0 ? 4 : 0));
                    tzm  = LD4(txzr + gzm);
                    tzzo = LD4(tzzr + gz);
                    tzzp = LD4(tzzr + gzp);
                    vxo  = LD4(vxr + gz);
                    vzo  = LD4(vzr + gz);
                } else {
                    int sOff = (z - zs0) * NX_ + x0i;
                    int vOff = (z - zv0) * NX_ + x0i;
                    txo  = LD4(txxl + sOff);
                    txn  = LD4(txxl + sOff + (x4i < NX4 - 1 ? 4 : 0));
                    tzo  = LD4(txzl + sOff);
                    tzp  = LD4(txzl + sOff - (x4i > 0 ? 4 : 0));
                    tzm  = LD4(txzl + sOff - NX_);
                    tzzo = LD4(tzzl + sOff);
                    tzzp = LD4(tzzl + sOff + NX_);
                    vxo  = LD4(vxl + vOff);
                    vzo  = LD4(vzl + vOff);
                }
                f4 bu = LD4(buoy + z * NX_ + x0i);
                f4 nvx, nvz;
#pragma unroll
                for (int e = 0; e < 4; ++e) {
                    int xg = x0i + e;
                    float txx_c = txo[e];
                    float txxp1 = (e == 3) ? txn[0] : txo[e + 1];
                    float txz_c = tzo[e];
                    float txzm1 = (e == 0) ? tzp[3] : tzo[e - 1];
                    float dxf_txx = (xg < NX_ - 1) ? (txxp1 - txx_c) / DH_ : 0.0f;
                    float dzb_txz = (z >= 1)       ? (txz_c - tzm[e]) / DH_ : 0.0f;
                    float dxb_txz = (xg >= 1)      ? (txz_c - txzm1) / DH_ : 0.0f;
                    float dzf_tzz = (z < NZ_ - 1)  ? (tzzp[e] - tzzo[e]) / DH_ : 0.0f;
                    nvx[e] = vxo[e] + bu[e] * (dxf_txx + dzb_txz);
                    nvz[e] = vzo[e] + bu[e] * (dxb_txz + dzf_tzz);
                }
                int vOff = (z - zv0) * NX_ + x0i;
                ST4(vxl + vOff, nvx);
                ST4(vzl + vOff, nvz);
                if (S == K_ - 1) {
                    if (z >= z0 && z < z0 + ROWS) {
                        ST4(vxw + base + z * NX_ + x0i, nvx);
                        ST4(vzw + base + z * NX_ + x0i, nvz);
                    }
                }
            }
        }
    }
    __syncthreads();

    // ---- receiver recording (post-velocity snapshot), owner tile only ----
    // out layout: (NT, NREC, 2B) — out[t, r, b]=vx, out[t, r, B+b]=vz
    if (rec_ok) {
        size_t o = ((size_t)t * NREC_ + tid) * (2 * B_);
        out[o + b]      = vxl[rec_idx];
        out[o + B_ + b] = vzl[rec_idx];
    }

    // ---- stress update on rows [z0-hs, z0+ROWS-1+hs] ----
    {
        constexpr int hs   = 2 * (K_ - 1 - S);
        constexpr int MAXR = ROWS + 2 * hs;
        constexpr int ITER = (MAXR * NX4 + NTHR - 1) / NTHR;
        const int zlo = imax_(0, z0 - hs);
        const int zhi = imin_(NZ_ - 1, z0 + ROWS - 1 + hs);
        const int n4  = (zhi - zlo + 1) * NX4;
#pragma unroll
        for (int it = 0; it < ITER; ++it) {
            int idx = tid + it * NTHR;
            if (idx < n4) {
                int dz  = idx / NX4;
                int x4i = idx - dz * NX4;
                int x0i = x4i * 4;
                int z   = zlo + dz;
                int vOff = (z - zv0) * NX_ + x0i;
                f4 vxo  = LD4(vxl + vOff);
                f4 vxp  = LD4(vxl + vOff - (x4i > 0 ? 4 : 0));
                f4 vxzp = LD4(vxl + vOff + NX_);
                f4 vzo  = LD4(vzl + vOff);
                f4 vzn  = LD4(vzl + vOff + (x4i < NX4 - 1 ? 4 : 0));
                f4 vzm  = LD4(vzl + vOff - NX_);
                f4 txxo, tzzo, txzo;
                if (S == 0) {
                    int gz = base + z * NX_ + x0i;
                    txxo = LD4(txxr + gz);
                    tzzo = LD4(tzzr + gz);
                    txzo = LD4(txzr + gz);
                } else {
                    int sOff = (z - zs0) * NX_ + x0i;
                    txxo = LD4(txxl + sOff);
                    tzzo = LD4(tzzl + sOff);
                    txzo = LD4(txzl + sOff);
                }
                int c0 = z * NX_ + x0i;
                f4 l   = LD4(lam  + c0);
                f4 lm  = LD4(l2m  + c0);
                f4 dtm = LD4(dtmu + c0);
                float w = wav[b * NT_ + t];
                f4 ntxx, ntzz, ntxz;
#pragma unroll
                for (int e = 0; e < 4; ++e) {
                    int xg = x0i + e;
                    float vx_c = vxo[e];
                    float vz_c = vzo[e];
                    float vxm1 = (e == 0) ? vxp[3] : vxo[e - 1];
                    float vzp1 = (e == 3) ? vzn[0] : vzo[e + 1];
                    float dvxdx  = (xg >= 1)      ? (vx_c - vxm1) / DH_ : 0.0f;
                    float dvzdz  = (z >= 1)       ? (vz_c - vzm[e]) / DH_ : 0.0f;
                    float dzf_vx = (z < NZ_ - 1)  ? (vxzp[e] - vx_c) / DH_ : 0.0f;
                    float dxf_vz = (xg < NX_ - 1) ? (vzp1 - vz_c) / DH_ : 0.0f;
                    float a  = txxo[e] + DT_ * (lm[e] * dvxdx + l[e] * dvzdz);
                    float bb = tzzo[e] + DT_ * (l[e] * dvxdx + lm[e] * dvzdz);
                    float cc = txzo[e] + dtm[e] * (dzf_vx + dxf_vz);
                    // source injection wherever the recompute range covers it
                    // (bit-identical across owner and halo-recomputing blocks)
                    if (z == sz && xg == sx) { a = a + w; bb = bb + w; }
                    ntxx[e] = a; ntzz[e] = bb; ntxz[e] = cc;
                }
                int sOff = (z - zs0) * NX_ + x0i;
                ST4(txxl + sOff, ntxx);
                ST4(tzzl + sOff, ntzz);
                ST4(txzl + sOff, ntxz);
                if (S == K_ - 1) {   // computed range == owned rows at last substep
                    int g = base + c0;
                    ST4(txxw + g, ntxx);
                    ST4(tzzw + g, ntzz);
                    ST4(txzw + g, ntxz);
                }
            }
        }
    }
    __syncthreads();
}

// ---------------- K_ fused timesteps, trapezoidal halo recompute ----------------
__global__ void __launch_bounds__(NTHR)
step_kernel(const float* __restrict__ vxr, const float* __restrict__ vzr,
            const float* __restrict__ txxr, const float* __restrict__ tzzr,
            const float* __restrict__ txzr,
            float* __restrict__ vxw, float* __restrict__ vzw,
            float* __restrict__ txxw, float* __restrict__ tzzw, float* __restrict__ txzw,
            const float* __restrict__ lam, const float* __restrict__ dtmu,
            const float* __restrict__ l2m, const float* __restrict__ buoy,
            const float* __restrict__ wav, int t0,
            const int* __restrict__ src_loc, const int* __restrict__ rec_loc,
            float* __restrict__ out) {
    extern __shared__ float smem[];
    float* __restrict__ vxl  = smem;                          // [VROWS][NX_]
    float* __restrict__ vzl  = vxl  + VROWS * NX_;
    float* __restrict__ txxl = vzl  + VROWS * NX_;            // [SROWSL][NX_]
    float* __restrict__ tzzl = txxl + SROWSL * NX_;
    float* __restrict__ txzl = tzzl + SROWSL * NX_;

    const int tid  = threadIdx.x;
    // XCD-aware swizzle (bijective: NBLK % 8 == 0): consecutive wg share an XCD,
    // so z-neighbor tiles exchange halos through the same L2 across dispatches.
    const int wg   = (blockIdx.x % NXCD) * (NBLK / NXCD) + blockIdx.x / NXCD;
    const int b    = wg / TILES;
    const int tile = wg % TILES;
    const int z0   = tile * ROWS;
    const int base = b * N_CELL;
    const int zv0  = z0 - VH;       // absolute z of vel LDS row 0
    const int zs0  = z0 - HS0;      // absolute z of stress LDS row 0

    const int sz = src_loc[2 * b];
    const int sx = src_loc[2 * b + 1];

    // receiver assignment hoisted out of the time loop
    bool rec_ok = false;
    int rec_idx = 0;
    if (tid < NREC_) {
        int rz = rec_loc[2 * tid];
        int rx = rec_loc[2 * tid + 1];
        if (rz >= z0 && rz < z0 + ROWS) {
            rec_ok = true;
            rec_idx = (rz - zv0) * NX_ + rx;
        }
    }

    substep<0>(tid, z0, base, zv0, zs0, sz, sx, b, t0, vxl, vzl, txxl, tzzl, txzl,
               vxr, vzr, txxr, tzzr, txzr, lam, dtmu, l2m, buoy, wav,
               rec_ok, rec_idx, out, vxw, vzw, txxw, tzzw, txzw);
    substep<1>(tid, z0, base, zv0, zs0, sz, sx, b, t0, vxl, vzl, txxl, tzzl, txzl,
               vxr, vzr, txxr, tzzr, txzr, lam, dtmu, l2m, buoy, wav,
               rec_ok, rec_idx, out, vxw, vzw, txxw, tzzw, txzw);
    substep<2>(tid, z0, base, zv0, zs0, sz, sx, b, t0, vxl, vzl, txxl, tzzl, txzl,
               vxr, vzr, txxr, tzzr, txzr, lam, dtmu, l2m, buoy, wav,
               rec_ok, rec_idx, out, vxw, vzw, txxw, tzzw, txzw);
    substep<3>(tid, z0, base, zv0, zs0, sz, sx, b, t0, vxl, vzl, txxl, tzzl, txzl,
               vxr, vzr, txxr, tzzr, txzr, lam, dtmu, l2m, buoy, wav,
               rec_ok, rec_idx, out, vxw, vzw, txxw, tzzw, txzw);
    substep<4>(tid, z0, base, zv0, zs0, sz, sx, b, t0, vxl, vzl, txxl, tzzl, txzl,
               vxr, vzr, txxr, tzzr, txzr, lam, dtmu, l2m, buoy, wav,
               rec_ok, rec_idx, out, vxw, vzw, txxw, tzzw, txzw);
    substep<5>(tid, z0, base, zv0, zs0, sz, sx, b, t0, vxl, vzl, txxl, tzzl, txzl,
               vxr, vzr, txxr, tzzr, txzr, lam, dtmu, l2m, buoy, wav,
               rec_ok, rec_idx, out, vxw, vzw, txxw, tzzw, txzw);
    substep<6>(tid, z0, base, zv0, zs0, sz, sx, b, t0, vxl, vzl, txxl, tzzl, txzl,
               vxr, vzr, txxr, tzzr, txzr, lam, dtmu, l2m, buoy, wav,
               rec_ok, rec_idx, out, vxw, vzw, txxw, tzzw, txzw);
    substep<7>(tid, z0, base, zv0, zs0, sz, sx, b, t0, vxl, vzl, txxl, tzzl, txzl,
               vxr, vzr, txxr, tzzr, txzr, lam, dtmu, l2m, buoy, wav,
               rec_ok, rec_idx, out, vxw, vzw, txxw, tzzw, txzw);
}

extern "C" void kernel_launch(void* const* d_in, const int* in_sizes, int n_in,
                              void* d_out, int out_size, void* d_ws, size_t ws_size,
                              hipStream_t stream) {
    const float* xw      = (const float*)d_in[0];   // (B, NT, 1)
    const float* vp      = (const float*)d_in[1];   // (NZ, NX)
    const float* vs      = (const float*)d_in[2];
    const float* rho     = (const float*)d_in[3];
    const int*   src_loc = (const int*)d_in[4];     // (B, 2)
    const int*   rec_loc = (const int*)d_in[5];     // (NREC, 2)
    float*       out     = (float*)d_out;

    float* ws = (float*)d_ws;
    // double-buffered wavefields
    float* vx[2]  = { ws + 0 * N_FIELD, ws + 1 * N_FIELD };
    float* vz[2]  = { ws + 2 * N_FIELD, ws + 3 * N_FIELD };
    float* txx[2] = { ws + 4 * N_FIELD, ws + 5 * N_FIELD };
    float* tzz[2] = { ws + 6 * N_FIELD, ws + 7 * N_FIELD };
    float* txz[2] = { ws + 8 * N_FIELD, ws + 9 * N_FIELD };
    float* lam    = ws + 10 * N_FIELD;
    float* dtmu   = lam + N_CELL;
    float* l2m    = dtmu + N_CELL;
    float* buoy   = l2m + N_CELL;

    // zero all wavefield buffers
    hipMemsetAsync(d_ws, 0, (size_t)10 * N_FIELD * sizeof(float), stream);

    mat_kernel<<<(N_CELL + 255) / 256, 256, 0, stream>>>(vp, vs, rho, lam, dtmu, l2m, buoy);

    for (int L = 0; L < NT_ / K_; ++L) {
        int p = L & 1;
        step_kernel<<<NBLK, NTHR, LDS_BYTES, stream>>>(
            vx[p], vz[p], txx[p], tzz[p], txz[p],
            vx[1 - p], vz[1 - p], txx[1 - p], tzz[1 - p], txz[1 - p],
            lam, dtmu, l2m, buoy,
            xw, L * K_, src_loc, rec_loc, out);
    }
}